// Round 1
// baseline (101.357 us; speedup 1.0000x reference)
//
#include <hip/hip_runtime.h>
#include <hip/hip_bf16.h>

// GCN layer: out = D^-1/2 A D^-1/2 (x W^T + b_lin) + bias
// N=8192, E=262144, DI=DO=128. A is a *set* adjacency (duplicates collapse),
// symmetric. We build an N x N bitmap (8 MB) with atomicOr (idempotent).

#define DIM 128
#define ROWS_PER_BLOCK 16
#define MAXN 1024  // max neighbors per row we support in LDS (actual max ~110)

__global__ void zero_kernel(unsigned int* __restrict__ p, long long n) {
    long long i = (long long)blockIdx.x * blockDim.x + threadIdx.x;
    if (i < n) p[i] = 0u;
}

// h[N,128] = x[N,128] @ W[128,128]^T + b_lin
__global__ __launch_bounds__(256) void linear_kernel(
    const float* __restrict__ x, const float* __restrict__ W,
    const float* __restrict__ b, float* __restrict__ h) {
    __shared__ float xt[ROWS_PER_BLOCK * DIM];
    const int block_row = blockIdx.x * ROWS_PER_BLOCK;
    const int tid = threadIdx.x;

    // stage 16 rows of x into LDS (float4, coalesced)
    const float4* xg = reinterpret_cast<const float4*>(x + (long long)block_row * DIM);
    float4* xl = reinterpret_cast<float4*>(xt);
    for (int i = tid; i < ROWS_PER_BLOCK * (DIM / 4); i += 256) xl[i] = xg[i];
    __syncthreads();

    const int d = tid & 127;     // output channel
    const int half = tid >> 7;   // row half (0..1), 8 rows each
    const float4* W4 = reinterpret_cast<const float4*>(W + (long long)d * DIM);

    float acc[8] = {0.f, 0.f, 0.f, 0.f, 0.f, 0.f, 0.f, 0.f};
    for (int k4 = 0; k4 < DIM / 4; ++k4) {
        const float4 w = W4[k4];
#pragma unroll
        for (int j = 0; j < 8; ++j) {
            const float4 xv =
                reinterpret_cast<const float4*>(xt + (half * 8 + j) * DIM)[k4];
            acc[j] += w.x * xv.x + w.y * xv.y + w.z * xv.z + w.w * xv.w;
        }
    }
    const float bb = b[d];
#pragma unroll
    for (int j = 0; j < 8; ++j) {
        h[(long long)(block_row + half * 8 + j) * DIM + d] = acc[j] + bb;
    }
}

__global__ void edge_kernel(const int* __restrict__ row, const int* __restrict__ col,
                            unsigned int* __restrict__ bitmap, int E, int WPR) {
    int e = blockIdx.x * blockDim.x + threadIdx.x;
    if (e >= E) return;
    const int r = row[e];
    const int c = col[e];
    atomicOr(bitmap + (long long)r * WPR + (c >> 5), 1u << (c & 31));
    atomicOr(bitmap + (long long)c * WPR + (r >> 5), 1u << (r & 31));
}

// one wave per row: degree via popcount, dinv = (deg + 1e-6)^-0.5
__global__ __launch_bounds__(64) void degree_kernel(
    const unsigned int* __restrict__ bitmap, float* __restrict__ dinv, int WPR) {
    const int i = blockIdx.x;
    const int lane = threadIdx.x;
    const unsigned int* rowp = bitmap + (long long)i * WPR;
    int cnt = 0;
    for (int w = lane; w < WPR; w += 64) cnt += __popc(rowp[w]);
#pragma unroll
    for (int off = 32; off > 0; off >>= 1) cnt += __shfl_down(cnt, off);
    if (lane == 0) dinv[i] = 1.0f / sqrtf((float)cnt + 1e-6f);
}

// one block (256 threads) per output row i:
//   phase A: bitmap row -> LDS neighbor list (+ weights dinv[j])
//   phase B: 2x128 threads gather-accumulate h[j,:], combine, scale, +bias
__global__ __launch_bounds__(256) void aggregate_kernel(
    const unsigned int* __restrict__ bitmap, const float* __restrict__ h,
    const float* __restrict__ dinv, const float* __restrict__ bias,
    float* __restrict__ out, int WPR) {
    __shared__ int nbr[MAXN];
    __shared__ float wgt[MAXN];
    __shared__ int wave_sums[4];
    __shared__ float partial[256];

    const int i = blockIdx.x;
    const int tid = threadIdx.x;
    const unsigned int* rowp = bitmap + (long long)i * WPR;

    // one 32-bit word per thread (WPR == 256 for N == 8192)
    unsigned int w = (tid < WPR) ? rowp[tid] : 0u;
    const int cnt = __popc(w);

    // inclusive scan across the block (wave-level shfl scan + wave offsets)
    const int lane = tid & 63;
    const int wave = tid >> 6;
    int scan = cnt;
#pragma unroll
    for (int off = 1; off < 64; off <<= 1) {
        const int v = __shfl_up(scan, off);
        if (lane >= off) scan += v;
    }
    if (lane == 63) wave_sums[wave] = scan;
    __syncthreads();
    int wave_off = 0;
    for (int k = 0; k < wave; ++k) wave_off += wave_sums[k];
    int base = wave_off + scan - cnt;  // exclusive prefix of this thread

    // decode bits -> neighbor indices + weights
    while (w) {
        const int b = __ffs(w) - 1;
        w &= w - 1;
        const int j = tid * 32 + b;
        if (base < MAXN) {
            nbr[base] = j;
            wgt[base] = dinv[j];
        }
        ++base;
    }
    __syncthreads();
    int cnt_total = wave_sums[0] + wave_sums[1] + wave_sums[2] + wave_sums[3];
    if (cnt_total > MAXN) cnt_total = MAXN;

    // phase B: channel d = tid&127, neighbor stride 2 by half
    const int d = tid & 127;
    const int half = tid >> 7;
    float acc = 0.f;
    for (int m = half; m < cnt_total; m += 2) {
        acc += wgt[m] * h[(long long)nbr[m] * DIM + d];
    }
    partial[tid] = acc;
    __syncthreads();
    if (tid < 128) {
        const float s = (partial[tid] + partial[tid + 128]) * dinv[i] + bias[tid];
        out[(long long)i * DIM + tid] = s;
    }
}

extern "C" void kernel_launch(void* const* d_in, const int* in_sizes, int n_in,
                              void* d_out, int out_size, void* d_ws, size_t ws_size,
                              hipStream_t stream) {
    const float* x = (const float*)d_in[0];
    const int* ei = (const int*)d_in[1];     // int32 per harness contract, [2, E]
    const float* W = (const float*)d_in[2];
    const float* b_lin = (const float*)d_in[3];
    const float* bias = (const float*)d_in[4];
    float* out = (float*)d_out;

    const int N = in_sizes[0] / DIM;   // 8192
    const int E = in_sizes[1] / 2;     // 262144
    const int WPR = (N + 31) >> 5;     // words per bitmap row (256)

    unsigned int* bitmap = (unsigned int*)d_ws;
    const long long bitmap_words = (long long)N * WPR;
    float* h = (float*)((char*)d_ws + bitmap_words * 4);
    float* dinv = h + (long long)N * DIM;

    zero_kernel<<<(int)((bitmap_words + 255) / 256), 256, 0, stream>>>(bitmap,
                                                                      bitmap_words);
    linear_kernel<<<N / ROWS_PER_BLOCK, 256, 0, stream>>>(x, W, b_lin, h);
    edge_kernel<<<(E + 255) / 256, 256, 0, stream>>>(ei, ei + E, bitmap, E, WPR);
    degree_kernel<<<N, 64, 0, stream>>>(bitmap, dinv, WPR);
    aggregate_kernel<<<N, 256, 0, stream>>>(bitmap, h, dinv, bias, out, WPR);
}

// Round 2
// 67.007 us; speedup vs baseline: 1.5126x; 1.5126x over previous
//
#include <hip/hip_runtime.h>
#include <hip/hip_bf16.h>

// GCN layer: out = D^-1/2 A D^-1/2 (x W^T + b_lin) + bias
// N=8192, E=262144, DI=DO=128. Set-semantics symmetric adjacency as an
// N x N bitmap (8 MB) built with idempotent atomicOr.
//
// Pipeline: hipMemsetAsync(bitmap) -> setup(linear || edge-scatter)
//           -> degree(popcount rows) -> aggregate(bitmap-decode + float4 gather)

#define DIM 128
#define ROWS_PER_BLOCK 16
#define MAXN 1024  // max neighbors per row supported in LDS (mean 64, Poisson tail << 1024)

// ---------------- fused setup: linear (blocks [0,nLin)) + edges (rest) ----------
__global__ __launch_bounds__(256) void setup_kernel(
    const float* __restrict__ x, const float* __restrict__ W,
    const float* __restrict__ b, float* __restrict__ h,
    const int* __restrict__ erow, const int* __restrict__ ecol,
    unsigned int* __restrict__ bitmap, int E, int WPR, int nLin) {
    const int tid = threadIdx.x;
    if ((int)blockIdx.x >= nLin) {
        // ---- edge scatter: 1 edge per thread ----
        const int e = ((int)blockIdx.x - nLin) * 256 + tid;
        if (e < E) {
            const int r = erow[e];
            const int c = ecol[e];
            atomicOr(bitmap + (long long)r * WPR + (c >> 5), 1u << (c & 31));
            atomicOr(bitmap + (long long)c * WPR + (r >> 5), 1u << (r & 31));
        }
        return;
    }
    // ---- linear: h[16 rows, 128] = x @ W^T + b ----
    __shared__ float xt[ROWS_PER_BLOCK * DIM];
    const int block_row = blockIdx.x * ROWS_PER_BLOCK;
    const float4* xg = reinterpret_cast<const float4*>(x + (long long)block_row * DIM);
    float4* xl = reinterpret_cast<float4*>(xt);
    for (int i = tid; i < ROWS_PER_BLOCK * (DIM / 4); i += 256) xl[i] = xg[i];
    __syncthreads();

    const int d = tid & 127;
    const int half = tid >> 7;
    const float4* W4 = reinterpret_cast<const float4*>(W + (long long)d * DIM);

    float acc[8] = {0.f, 0.f, 0.f, 0.f, 0.f, 0.f, 0.f, 0.f};
    for (int k4 = 0; k4 < DIM / 4; ++k4) {
        const float4 w = W4[k4];
#pragma unroll
        for (int j = 0; j < 8; ++j) {
            const float4 xv =
                reinterpret_cast<const float4*>(xt + (half * 8 + j) * DIM)[k4];
            acc[j] += w.x * xv.x + w.y * xv.y + w.z * xv.z + w.w * xv.w;
        }
    }
    const float bb = b[d];
#pragma unroll
    for (int j = 0; j < 8; ++j) {
        h[(long long)(block_row + half * 8 + j) * DIM + d] = acc[j] + bb;
    }
}

// ---------------- degree: 4 rows per block, one wave per row ----------------
__global__ __launch_bounds__(256) void degree_kernel(
    const unsigned int* __restrict__ bitmap, float* __restrict__ dinv, int WPR) {
    const int i = blockIdx.x * 4 + (threadIdx.x >> 6);
    const int lane = threadIdx.x & 63;
    const unsigned int* rowp = bitmap + (long long)i * WPR;
    int cnt = 0;
    for (int w = lane; w < WPR; w += 64) cnt += __popc(rowp[w]);
#pragma unroll
    for (int off = 32; off > 0; off >>= 1) cnt += __shfl_down(cnt, off);
    if (lane == 0) dinv[i] = rsqrtf((float)cnt + 1e-6f);
}

// ---------------- aggregate: one block per row ------------------------------
// phase A: bitmap row -> compact LDS neighbor list + weights dinv[j]
// phase B: 8 neighbor-groups x 32 lanes, float4 gather, 4 loads in flight
__global__ __launch_bounds__(256) void aggregate_kernel(
    const unsigned int* __restrict__ bitmap, const float4* __restrict__ h4,
    const float* __restrict__ dinv, const float4* __restrict__ bias4,
    float4* __restrict__ out4, int WPR) {
    __shared__ int nbr[MAXN];
    __shared__ float wgt[MAXN];
    __shared__ int wave_sums[4];
    __shared__ float4 partial[8 * 32];

    const int i = blockIdx.x;
    const int tid = threadIdx.x;
    const float d_i = dinv[i];  // block-uniform -> s_load, issued early
    const unsigned int* rowp = bitmap + (long long)i * WPR;

    unsigned int w = (tid < WPR) ? rowp[tid] : 0u;
    const int cnt = __popc(w);

    // block-wide exclusive scan (wave shfl scan + wave offsets)
    const int lane = tid & 63;
    const int wave = tid >> 6;
    int scan = cnt;
#pragma unroll
    for (int off = 1; off < 64; off <<= 1) {
        const int v = __shfl_up(scan, off);
        if (lane >= off) scan += v;
    }
    if (lane == 63) wave_sums[wave] = scan;
    __syncthreads();
    int wave_off = 0;
    for (int k = 0; k < wave; ++k) wave_off += wave_sums[k];
    int base = wave_off + scan - cnt;

    while (w) {
        const int bpos = __ffs(w) - 1;
        w &= w - 1;
        const int j = tid * 32 + bpos;
        if (base < MAXN) {
            nbr[base] = j;
            wgt[base] = dinv[j];
        }
        ++base;
    }
    __syncthreads();
    int cnt_total = wave_sums[0] + wave_sums[1] + wave_sums[2] + wave_sums[3];
    if (cnt_total > MAXN) cnt_total = MAXN;

    // ---- phase B ----
    const int c = tid & 31;   // float4 channel slot (128 ch = 32 x float4)
    const int g = tid >> 5;   // neighbor group 0..7
    float ax = 0.f, ay = 0.f, az = 0.f, aw = 0.f;

    int m = g;
    for (; m + 24 < cnt_total; m += 32) {
        const int j0 = nbr[m], j1 = nbr[m + 8], j2 = nbr[m + 16], j3 = nbr[m + 24];
        const float w0 = wgt[m], w1 = wgt[m + 8], w2 = wgt[m + 16], w3 = wgt[m + 24];
        const float4 v0 = h4[(j0 << 5) + c];
        const float4 v1 = h4[(j1 << 5) + c];
        const float4 v2 = h4[(j2 << 5) + c];
        const float4 v3 = h4[(j3 << 5) + c];
        ax += w0 * v0.x; ay += w0 * v0.y; az += w0 * v0.z; aw += w0 * v0.w;
        ax += w1 * v1.x; ay += w1 * v1.y; az += w1 * v1.z; aw += w1 * v1.w;
        ax += w2 * v2.x; ay += w2 * v2.y; az += w2 * v2.z; aw += w2 * v2.w;
        ax += w3 * v3.x; ay += w3 * v3.y; az += w3 * v3.z; aw += w3 * v3.w;
    }
    for (; m < cnt_total; m += 8) {
        const int j = nbr[m];
        const float wm = wgt[m];
        const float4 v = h4[(j << 5) + c];
        ax += wm * v.x; ay += wm * v.y; az += wm * v.z; aw += wm * v.w;
    }
    partial[tid].x = ax; partial[tid].y = ay;
    partial[tid].z = az; partial[tid].w = aw;
    __syncthreads();

    if (tid < 32) {
        float4 s = partial[tid];
#pragma unroll
        for (int k = 1; k < 8; ++k) {
            const float4 p = partial[k * 32 + tid];
            s.x += p.x; s.y += p.y; s.z += p.z; s.w += p.w;
        }
        const float4 bb = bias4[tid];
        float4 o;
        o.x = s.x * d_i + bb.x;
        o.y = s.y * d_i + bb.y;
        o.z = s.z * d_i + bb.z;
        o.w = s.w * d_i + bb.w;
        out4[(long long)i * 32 + tid] = o;
    }
}

extern "C" void kernel_launch(void* const* d_in, const int* in_sizes, int n_in,
                              void* d_out, int out_size, void* d_ws, size_t ws_size,
                              hipStream_t stream) {
    const float* x = (const float*)d_in[0];
    const int* ei = (const int*)d_in[1];  // int32 per harness contract, [2, E]
    const float* W = (const float*)d_in[2];
    const float* b_lin = (const float*)d_in[3];
    const float* bias = (const float*)d_in[4];
    float* out = (float*)d_out;

    const int N = in_sizes[0] / DIM;   // 8192
    const int E = in_sizes[1] / 2;     // 262144
    const int WPR = (N + 31) >> 5;     // 256 words per bitmap row

    unsigned int* bitmap = (unsigned int*)d_ws;
    const long long bitmap_bytes = (long long)N * WPR * 4;
    float* h = (float*)((char*)d_ws + bitmap_bytes);
    float* dinv = h + (long long)N * DIM;

    hipMemsetAsync(bitmap, 0, (size_t)bitmap_bytes, stream);

    const int nLin = N / ROWS_PER_BLOCK;        // 512
    const int nEdge = (E + 255) / 256;          // 1024
    setup_kernel<<<nLin + nEdge, 256, 0, stream>>>(x, W, b_lin, h, ei, ei + E,
                                                   bitmap, E, WPR, nLin);
    degree_kernel<<<N / 4, 256, 0, stream>>>(bitmap, dinv, WPR);
    aggregate_kernel<<<N, 256, 0, stream>>>(bitmap, (const float4*)h, dinv,
                                            (const float4*)bias, (float4*)out, WPR);
}